// Round 11
// baseline (216.371 us; speedup 1.0000x reference)
//
#include <hip/hip_runtime.h>

// EdgeLoss: weighted BCE-with-logits mean over 32x1x768x1024 fp32 tensors.
// result = (neg_num * S_pos + pos_num * S_neg) / (pos_num + neg_num) / n
// S_pos = sum over t==1 of bce(x,1), S_neg = sum over t==0 of bce(x,0),
// bce(x,t) = max(x,0) - x*t + log(1+exp(-|x|)).
//
// R10 -> R11: single-variable ablation of the NT hint. R8's win changed two
// things (contiguous segments + NT loads). Hypothesis: the harness's d_in
// restore (201 MB D2D copy right before each launch) leaves inputs
// write-back-resident in the 256 MiB L3 (pre-R8 profiles: FETCH 98 MB for
// 201 MB of single-pass reads = 50% L3 hit, only explicable as restore
// leftovers). NT/evict-first refuses that reuse and forces full-HBM reads.
// This round: R10 exactly, with plain loads. If L3-leftover theory is
// right, stage1 drops ~10-20 us; if neutral, both paths are at the
// dual-stream read ceiling and we're done.

#define GRID1 2048
#define BLOCK 256
#define NACC 5

typedef float floatx4 __attribute__((ext_vector_type(4)));

__device__ __forceinline__ void do_elem(float xv, float tv,
                                        float& cnt_all, float& cnt_pos,
                                        float& sum_c, float& sum_tc,
                                        float& sum_tx) {
  float a = fabsf(xv);
  float e = __expf(-a);                  // v_exp_f32
  float l = __logf(1.0f + e);            // v_log_f32
  float c = fmaxf(xv, 0.f) + l;          // softplus(x): bce(t=0)=c, bce(t=1)=c-x
  bool valid = (tv < 1.5f);              // t in {0,1}
  float tm = valid ? tv : 0.0f;          // 1 for pos, 0 otherwise (t exact)
  cnt_all += valid ? 1.0f : 0.0f;
  cnt_pos += tm;
  sum_c   += valid ? c : 0.0f;
  sum_tc   = fmaf(tm, c, sum_tc);
  sum_tx   = fmaf(tm, xv, sum_tx);
}

__device__ __forceinline__ void do_vec4(floatx4 xv, floatx4 tv,
                                        float& a0, float& a1, float& a2,
                                        float& a3, float& a4) {
  do_elem(xv.x, tv.x, a0, a1, a2, a3, a4);
  do_elem(xv.y, tv.y, a0, a1, a2, a3, a4);
  do_elem(xv.z, tv.z, a0, a1, a2, a3, a4);
  do_elem(xv.w, tv.w, a0, a1, a2, a3, a4);
}

__global__ __launch_bounds__(BLOCK, 8) void edge_loss_stage1(
    const float* __restrict__ x, const float* __restrict__ t,
    float* __restrict__ partials, long long n) {
  long long n4 = n >> 2;
  // Contiguous per-block segment [beg, end): 2048 independent sequential
  // DRAM streams (R8's bank-parallelism win).
  long long per = (n4 + gridDim.x - 1) / gridDim.x;
  long long beg = (long long)blockIdx.x * per;
  long long end = beg + per < n4 ? beg + per : n4;

  const floatx4* __restrict__ x4 = (const floatx4*)x;
  const floatx4* __restrict__ t4 = (const floatx4*)t;

  float a0 = 0.f, a1 = 0.f, a2 = 0.f, a3 = 0.f, a4 = 0.f;

  #pragma unroll 2
  for (long long i = beg + threadIdx.x; i < end; i += BLOCK) {
    floatx4 xv = x4[i];                  // plain load: allow L3 hits from
    floatx4 tv = t4[i];                  // the harness's d_in restore
    do_vec4(xv, tv, a0, a1, a2, a3, a4);
  }
  // scalar tail (n not a multiple of 4), grid-stride across all blocks
  for (long long j = (n4 << 2) + (long long)blockIdx.x * BLOCK + threadIdx.x;
       j < n; j += (long long)gridDim.x * BLOCK) {
    do_elem(x[j], t[j], a0, a1, a2, a3, a4);
  }

  // wave-64 shuffle reduction
  #pragma unroll
  for (int off = 32; off > 0; off >>= 1) {
    a0 += __shfl_down(a0, off, 64);
    a1 += __shfl_down(a1, off, 64);
    a2 += __shfl_down(a2, off, 64);
    a3 += __shfl_down(a3, off, 64);
    a4 += __shfl_down(a4, off, 64);
  }

  __shared__ float s_acc[4][NACC];
  int lane = threadIdx.x & 63;
  int wave = threadIdx.x >> 6;
  if (lane == 0) {
    s_acc[wave][0] = a0; s_acc[wave][1] = a1; s_acc[wave][2] = a2;
    s_acc[wave][3] = a3; s_acc[wave][4] = a4;
  }
  __syncthreads();
  if (threadIdx.x == 0) {
    float r[NACC] = {0.f, 0.f, 0.f, 0.f, 0.f};
    #pragma unroll
    for (int w = 0; w < 4; ++w)
      #pragma unroll
      for (int c = 0; c < NACC; ++c) r[c] += s_acc[w][c];
    int G = gridDim.x;
    #pragma unroll
    for (int c = 0; c < NACC; ++c) partials[c * G + blockIdx.x] = r[c];
  }
}

__global__ __launch_bounds__(BLOCK) void edge_loss_stage2(
    const float* __restrict__ partials, float* __restrict__ out,
    int G, double inv_n) {
  double acc[NACC] = {0.0, 0.0, 0.0, 0.0, 0.0};
  for (int i = threadIdx.x; i < G; i += BLOCK) {
    #pragma unroll
    for (int c = 0; c < NACC; ++c) acc[c] += (double)partials[c * G + i];
  }
  #pragma unroll
  for (int off = 32; off > 0; off >>= 1) {
    #pragma unroll
    for (int c = 0; c < NACC; ++c) acc[c] += __shfl_down(acc[c], off, 64);
  }
  __shared__ double s_acc[4][NACC];
  int lane = threadIdx.x & 63;
  int wave = threadIdx.x >> 6;
  if (lane == 0) {
    #pragma unroll
    for (int c = 0; c < NACC; ++c) s_acc[wave][c] = acc[c];
  }
  __syncthreads();
  if (threadIdx.x == 0) {
    double r[NACC] = {0.0, 0.0, 0.0, 0.0, 0.0};
    #pragma unroll
    for (int w = 0; w < 4; ++w)
      #pragma unroll
      for (int c = 0; c < NACC; ++c) r[c] += s_acc[w][c];
    double pos  = r[1];
    double neg  = r[0] - r[1];
    double spos = r[3] - r[4];        // sum_tc - sum_tx
    double sneg = r[2] - r[3];        // sum_c  - sum_tc
    double s = pos + neg;
    out[0] = (float)((neg * spos + pos * sneg) / s * inv_n);
  }
}

extern "C" void kernel_launch(void* const* d_in, const int* in_sizes, int n_in,
                              void* d_out, int out_size, void* d_ws, size_t ws_size,
                              hipStream_t stream) {
  const float* x = (const float*)d_in[0];
  const float* t = (const float*)d_in[1];
  long long n = (long long)in_sizes[0];
  float* partials = (float*)d_ws;  // NACC * GRID1 floats = 40 KB, fully written

  edge_loss_stage1<<<GRID1, BLOCK, 0, stream>>>(x, t, partials, n);
  edge_loss_stage2<<<1, BLOCK, 0, stream>>>(partials, (float*)d_out,
                                            GRID1, 1.0 / (double)n);
}

// Round 12
// 196.110 us; speedup vs baseline: 1.1033x; 1.1033x over previous
//
#include <hip/hip_runtime.h>

// EdgeLoss: weighted BCE-with-logits mean over 32x1x768x1024 fp32 tensors.
// result = (neg_num * S_pos + pos_num * S_neg) / (pos_num + neg_num) / n
// S_pos = sum over t==1 of bce(x,1), S_neg = sum over t==0 of bce(x,0),
// bce(x,t) = max(x,0) - x*t + log(1+exp(-|x|)).
//
// R11 -> R12: REVERT to measured-best R10. R11's ablation proved the
// nontemporal hint is load-path-essential (plain loads: 216 us / stage1
// 80 us; NT: 197.8 us / stage1 ~55 us). The plain-load path serves ~50%
// of reads from L3 (FETCH 98 MB of 201 MB) but at only ~2.5 TB/s -- the
// L3-hit path is SLOWER than NT streaming straight from HBM (~3.6 TB/s).
// All other levers tested and neutral/negative: reg-batch MLP (R5),
// LDS-DMA dbuf prefetch with and without NT (R6/R9), VALU-reduced body
// (R10), NT ablation (R11). Remaining bench time is dominated by the
// ~143 us harness restore/poison floor (top-5 = fillBufferAligned).

#define GRID1 2048
#define BLOCK 256
#define NACC 5

typedef float floatx4 __attribute__((ext_vector_type(4)));

__device__ __forceinline__ void do_elem(float xv, float tv,
                                        float& cnt_all, float& cnt_pos,
                                        float& sum_c, float& sum_tc,
                                        float& sum_tx) {
  float a = fabsf(xv);
  float e = __expf(-a);                  // v_exp_f32
  float l = __logf(1.0f + e);            // v_log_f32
  float c = fmaxf(xv, 0.f) + l;          // softplus(x): bce(t=0)=c, bce(t=1)=c-x
  bool valid = (tv < 1.5f);              // t in {0,1}
  float tm = valid ? tv : 0.0f;          // 1 for pos, 0 otherwise (t exact)
  cnt_all += valid ? 1.0f : 0.0f;
  cnt_pos += tm;
  sum_c   += valid ? c : 0.0f;
  sum_tc   = fmaf(tm, c, sum_tc);
  sum_tx   = fmaf(tm, xv, sum_tx);
}

__device__ __forceinline__ void do_vec4(floatx4 xv, floatx4 tv,
                                        float& a0, float& a1, float& a2,
                                        float& a3, float& a4) {
  do_elem(xv.x, tv.x, a0, a1, a2, a3, a4);
  do_elem(xv.y, tv.y, a0, a1, a2, a3, a4);
  do_elem(xv.z, tv.z, a0, a1, a2, a3, a4);
  do_elem(xv.w, tv.w, a0, a1, a2, a3, a4);
}

__global__ __launch_bounds__(BLOCK, 8) void edge_loss_stage1(
    const float* __restrict__ x, const float* __restrict__ t,
    float* __restrict__ partials, long long n) {
  long long n4 = n >> 2;
  // Contiguous per-block segment [beg, end): 2048 independent sequential
  // DRAM streams.
  long long per = (n4 + gridDim.x - 1) / gridDim.x;
  long long beg = (long long)blockIdx.x * per;
  long long end = beg + per < n4 ? beg + per : n4;

  const floatx4* __restrict__ x4 = (const floatx4*)x;
  const floatx4* __restrict__ t4 = (const floatx4*)t;

  float a0 = 0.f, a1 = 0.f, a2 = 0.f, a3 = 0.f, a4 = 0.f;

  #pragma unroll 2
  for (long long i = beg + threadIdx.x; i < end; i += BLOCK) {
    floatx4 xv = __builtin_nontemporal_load(&x4[i]);  // NT: skip the slow
    floatx4 tv = __builtin_nontemporal_load(&t4[i]);  // L3-hit path (R11)
    do_vec4(xv, tv, a0, a1, a2, a3, a4);
  }
  // scalar tail (n not a multiple of 4), grid-stride across all blocks
  for (long long j = (n4 << 2) + (long long)blockIdx.x * BLOCK + threadIdx.x;
       j < n; j += (long long)gridDim.x * BLOCK) {
    do_elem(x[j], t[j], a0, a1, a2, a3, a4);
  }

  // wave-64 shuffle reduction
  #pragma unroll
  for (int off = 32; off > 0; off >>= 1) {
    a0 += __shfl_down(a0, off, 64);
    a1 += __shfl_down(a1, off, 64);
    a2 += __shfl_down(a2, off, 64);
    a3 += __shfl_down(a3, off, 64);
    a4 += __shfl_down(a4, off, 64);
  }

  __shared__ float s_acc[4][NACC];
  int lane = threadIdx.x & 63;
  int wave = threadIdx.x >> 6;
  if (lane == 0) {
    s_acc[wave][0] = a0; s_acc[wave][1] = a1; s_acc[wave][2] = a2;
    s_acc[wave][3] = a3; s_acc[wave][4] = a4;
  }
  __syncthreads();
  if (threadIdx.x == 0) {
    float r[NACC] = {0.f, 0.f, 0.f, 0.f, 0.f};
    #pragma unroll
    for (int w = 0; w < 4; ++w)
      #pragma unroll
      for (int c = 0; c < NACC; ++c) r[c] += s_acc[w][c];
    int G = gridDim.x;
    #pragma unroll
    for (int c = 0; c < NACC; ++c) partials[c * G + blockIdx.x] = r[c];
  }
}

__global__ __launch_bounds__(BLOCK) void edge_loss_stage2(
    const float* __restrict__ partials, float* __restrict__ out,
    int G, double inv_n) {
  double acc[NACC] = {0.0, 0.0, 0.0, 0.0, 0.0};
  for (int i = threadIdx.x; i < G; i += BLOCK) {
    #pragma unroll
    for (int c = 0; c < NACC; ++c) acc[c] += (double)partials[c * G + i];
  }
  #pragma unroll
  for (int off = 32; off > 0; off >>= 1) {
    #pragma unroll
    for (int c = 0; c < NACC; ++c) acc[c] += __shfl_down(acc[c], off, 64);
  }
  __shared__ double s_acc[4][NACC];
  int lane = threadIdx.x & 63;
  int wave = threadIdx.x >> 6;
  if (lane == 0) {
    #pragma unroll
    for (int c = 0; c < NACC; ++c) s_acc[wave][c] = acc[c];
  }
  __syncthreads();
  if (threadIdx.x == 0) {
    double r[NACC] = {0.0, 0.0, 0.0, 0.0, 0.0};
    #pragma unroll
    for (int w = 0; w < 4; ++w)
      #pragma unroll
      for (int c = 0; c < NACC; ++c) r[c] += s_acc[w][c];
    double pos  = r[1];
    double neg  = r[0] - r[1];
    double spos = r[3] - r[4];        // sum_tc - sum_tx
    double sneg = r[2] - r[3];        // sum_c  - sum_tc
    double s = pos + neg;
    out[0] = (float)((neg * spos + pos * sneg) / s * inv_n);
  }
}

extern "C" void kernel_launch(void* const* d_in, const int* in_sizes, int n_in,
                              void* d_out, int out_size, void* d_ws, size_t ws_size,
                              hipStream_t stream) {
  const float* x = (const float*)d_in[0];
  const float* t = (const float*)d_in[1];
  long long n = (long long)in_sizes[0];
  float* partials = (float*)d_ws;  // NACC * GRID1 floats = 40 KB, fully written

  edge_loss_stage1<<<GRID1, BLOCK, 0, stream>>>(x, t, partials, n);
  edge_loss_stage2<<<1, BLOCK, 0, stream>>>(partials, (float*)d_out,
                                            GRID1, 1.0 / (double)n);
}